// Round 1
// baseline (736.518 us; speedup 1.0000x reference)
//
#include <hip/hip_runtime.h>
#include <math.h>

constexpr int BATCH = 16;
constexpr int NI = 1024;   // nodes
constexpr int CE = 64;     // emb channels
constexpr int CI = 16;     // input channels
constexpr long long NN2  = (long long)NI * NI;          // 1M
constexpr long long BCN  = (long long)BATCH * CE * NI;  // 1M
constexpr long long B2CN = 2 * BCN;                     // 2M
constexpr long long BNv  = (long long)BATCH * NI;       // 16K
constexpr long long BNN  = (long long)BATCH * NI * NI;  // 16M
constexpr long long S1 = (long long)CE * NI;            // 65536
constexpr long long S2 = 2 * S1;                        // 131072

#define GF_RELU 1
#define GF_ACCUM 2
#define GF_TRANSB 4

__device__ __forceinline__ float lrelu01(float x) { return x > 0.f ? x : 0.01f * x; }

// ---------------- generic tiled fp32 GEMM: C[r,m] = sum_k A[r,k]*B[k,m] -------------
// lda = K, ldb = (TRANSB ? K : M) (TRANSB: B stored [M,K]), ldc = M.
// Dims must be multiples of tile sizes (true for all uses here).
__global__ __launch_bounds__(256) void gemm64(
    const float* __restrict__ A, const float* __restrict__ Bm, float* __restrict__ C,
    const float* __restrict__ colbias, const float* __restrict__ rowbias,
    const float* __restrict__ rowdiv, int rowdivStride,
    int K, int M, long long bsA, long long bsB, long long bsC, int flags)
{
  __shared__ float As[16][64];
  __shared__ float Bs[16][64];
  const int z = blockIdx.z;
  const int m0 = blockIdx.x * 64;
  const int r0 = blockIdx.y * 64;
  const float* Ab = A + (long long)z * bsA;
  const float* Bp = Bm + (long long)z * bsB;
  float* Cb = C + (long long)z * bsC;
  const int tid = threadIdx.x;
  const int tx = tid & 15, ty = tid >> 4;
  const int lr = tid >> 2;          // 0..63
  const int lk = (tid & 3) << 2;    // 0,4,8,12
  const int bkr = tid >> 4;         // 0..15
  const int bmc = (tid & 15) << 2;  // 0..60

  float acc[4][4] = {};

  for (int k0 = 0; k0 < K; k0 += 16) {
    float4 av = *(const float4*)(Ab + (long long)(r0 + lr) * K + k0 + lk);
    As[lk + 0][lr] = av.x; As[lk + 1][lr] = av.y;
    As[lk + 2][lr] = av.z; As[lk + 3][lr] = av.w;
    if (flags & GF_TRANSB) {
      float4 bv = *(const float4*)(Bp + (long long)(m0 + lr) * K + k0 + lk);
      Bs[lk + 0][lr] = bv.x; Bs[lk + 1][lr] = bv.y;
      Bs[lk + 2][lr] = bv.z; Bs[lk + 3][lr] = bv.w;
    } else {
      float4 bv = *(const float4*)(Bp + (long long)(k0 + bkr) * M + m0 + bmc);
      *(float4*)&Bs[bkr][bmc] = bv;
    }
    __syncthreads();
#pragma unroll
    for (int kk = 0; kk < 16; kk++) {
      float4 a = *(const float4*)&As[kk][ty << 2];
      float4 b = *(const float4*)&Bs[kk][tx << 2];
      float av4[4] = {a.x, a.y, a.z, a.w};
      float bv4[4] = {b.x, b.y, b.z, b.w};
#pragma unroll
      for (int i = 0; i < 4; i++)
#pragma unroll
        for (int j = 0; j < 4; j++)
          acc[i][j] = fmaf(av4[i], bv4[j], acc[i][j]);
    }
    __syncthreads();
  }

#pragma unroll
  for (int i = 0; i < 4; i++) {
    const int r = r0 + (ty << 2) + i;
    float rs = 1.f;
    if (rowdiv) rs = 1.f / rowdiv[(long long)z * rowdivStride + r];
    const float rb = rowbias ? rowbias[r] : 0.f;
#pragma unroll
    for (int j = 0; j < 4; j++) {
      const int m = m0 + (tx << 2) + j;
      float v = acc[i][j] * rs + rb;
      if (colbias) v += colbias[m];
      if (flags & GF_RELU) v = fmaxf(v, 0.f);
      float* cp = Cb + (long long)r * M + m;
      if (flags & GF_ACCUM) v += *cp;
      *cp = v;
    }
  }
}

// ---------------- 32x32 transpose: out[n][m] = in[m][n], both NIxNI ------------------
__global__ __launch_bounds__(256) void transpose_k(const float* __restrict__ in,
                                                   float* __restrict__ out)
{
  __shared__ float t[32][33];
  const int bx = blockIdx.x * 32, by = blockIdx.y * 32;
  const int lx = threadIdx.x, ly = threadIdx.y;  // 32x8
  for (int yy = ly; yy < 32; yy += 8)
    t[yy][lx] = in[(long long)(by + yy) * NI + bx + lx];
  __syncthreads();
  for (int yy = ly; yy < 32; yy += 8)
    out[(long long)(bx + yy) * NI + by + lx] = t[lx][yy];
}

// pack [lin1_w; lin2_w] -> stackW[128][64], rowbias128 = {0..0, lin2_b}
__global__ void pack_kernel(const float* __restrict__ l1w, const float* __restrict__ l2w,
                            const float* __restrict__ l2b, float* __restrict__ stackW,
                            float* __restrict__ rb128)
{
  const int t = blockIdx.x * 256 + threadIdx.x;  // 8192 total
  if (t < 4096) stackW[t] = l1w[t];
  else stackW[t] = l2w[t - 4096];
  if (t < 64) rb128[t] = 0.f;
  else if (t < 128) rb128[t] = l2b[t - 64];
}

// laplacian: dr[k][i] = rsqrt(1 + sum_j graph[k][i][j])   (eye adds 1 to the row)
__global__ __launch_bounds__(256) void lap_rowsum(const float* __restrict__ gd,
                                                  float* __restrict__ dr)
{
  const int ki = blockIdx.x;  // 2*NI
  const int k = ki >> 10, i = ki & 1023;
  const float* row = gd + (long long)k * NN2 + (long long)i * NI;
  float s = 0.f;
  for (int j = threadIdx.x; j < NI; j += 256) s += row[j];
  __shared__ float red[256];
  red[threadIdx.x] = s; __syncthreads();
  for (int st = 128; st > 0; st >>= 1) {
    if (threadIdx.x < st) red[threadIdx.x] += red[threadIdx.x + st];
    __syncthreads();
  }
  if (threadIdx.x == 0) dr[ki] = rsqrtf(red[0] + 1.f);
}

// g[i][j] = (graph[k][j][i] + (i==j)) * d[i] * d[j]
__global__ __launch_bounds__(256) void lap_build(const float* __restrict__ gd,
                                                 const float* __restrict__ dr,
                                                 float* __restrict__ g1,
                                                 float* __restrict__ g2)
{
  const int k = blockIdx.z;
  const float* m = gd + (long long)k * NN2;
  const float* d = dr + k * NI;
  float* out = k ? g2 : g1;
  __shared__ float t[32][33];
  const int bx = blockIdx.x * 32, by = blockIdx.y * 32;
  const int lx = threadIdx.x, ly = threadIdx.y;  // 32x8
  for (int yy = ly; yy < 32; yy += 8)
    t[yy][lx] = m[(long long)(bx + yy) * NI + by + lx];
  __syncthreads();
  for (int yy = ly; yy < 32; yy += 8) {
    const int i = by + yy, j = bx + lx;
    float v = t[lx][yy] + (i == j ? 1.f : 0.f);
    out[(long long)i * NI + j] = v * d[i] * d[j];
  }
}

// h0a[b,e,n] = lrelu(sum_c x[b,c,n]*emb_w[e,c] + emb_b[e])
__global__ __launch_bounds__(256) void conv_emb(const float* __restrict__ x,
                                                const float* __restrict__ ew,
                                                const float* __restrict__ eb,
                                                float* __restrict__ h0a)
{
  const int be = blockIdx.x;  // b*64+e
  const int b = be >> 6, e = be & 63;
  __shared__ float w[CI];
  if (threadIdx.x < CI) w[threadIdx.x] = ew[e * CI + threadIdx.x];
  __syncthreads();
  const float bias = eb[e];
  const float* xb = x + (long long)b * CI * NI;
  float* outp = h0a + (long long)be * NI;
  for (int n = threadIdx.x; n < NI; n += 256) {
    float a = bias;
#pragma unroll
    for (int c = 0; c < CI; c++) a = fmaf(xb[c * NI + n], w[c], a);
    outp[n] = lrelu01(a);
  }
}

// h[b,n,k] = sum_c h0[b,c,n]*att_W[c,k];  s1[b,n]=h.a1, s2[b,n]=h.a2 (wave reductions)
__global__ __launch_bounds__(256) void h_s_kernel(const float* __restrict__ h0,
                                                  const float* __restrict__ attW,
                                                  const float* __restrict__ atta,
                                                  float* __restrict__ h,
                                                  float* __restrict__ s1,
                                                  float* __restrict__ s2)
{
  const int lane = threadIdx.x & 63;
  const int wv = threadIdx.x >> 6;
  const int bn = blockIdx.x * 4 + wv;  // grid = BN/4
  const int b = bn >> 10, n = bn & 1023;
  const float* h0b = h0 + (long long)b * CE * NI + n;
  float acc = 0.f;
#pragma unroll 8
  for (int c = 0; c < CE; c++)
    acc = fmaf(h0b[(long long)c * NI], attW[c * CE + lane], acc);
  h[(long long)bn * CE + lane] = acc;
  float v1 = acc * atta[lane];
  float v2 = acc * atta[CE + lane];
  for (int off = 32; off > 0; off >>= 1) {
    v1 += __shfl_down(v1, off);
    v2 += __shfl_down(v2, off);
  }
  if (lane == 0) { s1[bn] = v1; s2[bn] = v2; }
}

__global__ __launch_bounds__(256) void s2max_kernel(const float* __restrict__ s2,
                                                    float* __restrict__ s2m)
{
  const int b = blockIdx.x;
  float m = -3.4e38f;
  for (int n = threadIdx.x; n < NI; n += 256) m = fmaxf(m, s2[b * NI + n]);
  __shared__ float red[256];
  red[threadIdx.x] = m; __syncthreads();
  for (int st = 128; st > 0; st >>= 1) {
    if (threadIdx.x < st) red[threadIdx.x] = fmaxf(red[threadIdx.x], red[threadIdx.x + st]);
    __syncthreads();
  }
  if (threadIdx.x == 0) s2m[b] = red[0];
}

// p[b,i,j] = exp(lrelu(s1_i+s2_j) - lrelu(s1_i+s2max));  Zatt[b,i] = sum_j p
__global__ __launch_bounds__(256) void att_p(const float* __restrict__ s1,
                                             const float* __restrict__ s2,
                                             const float* __restrict__ s2m,
                                             float* __restrict__ Wp,
                                             float* __restrict__ Zatt)
{
  const int i = blockIdx.x;  // NI
  const int b = blockIdx.y;  // BATCH
  const float s1i = s1[b * NI + i];
  const float m = lrelu01(s1i + s2m[b]);
  const float* s2b = s2 + b * NI;
  float* row = Wp + (long long)b * NN2 + (long long)i * NI;
  float lsum = 0.f;
  for (int j = threadIdx.x; j < NI; j += 256) {
    float p = __expf(lrelu01(s1i + s2b[j]) - m);
    row[j] = p;
    lsum += p;
  }
  __shared__ float red[256];
  red[threadIdx.x] = lsum; __syncthreads();
  for (int st = 128; st > 0; st >>= 1) {
    if (threadIdx.x < st) red[threadIdx.x] += red[threadIdx.x + st];
    __syncthreads();
  }
  if (threadIdx.x == 0) Zatt[b * NI + i] = red[0];
}

// sq[b,n] = sum_c x_uai[b,c,n]^2
__global__ __launch_bounds__(256) void sq_kernel(const float* __restrict__ xu,
                                                 float* __restrict__ sq)
{
  const int bn = blockIdx.x * 256 + threadIdx.x;  // BN total
  const int b = bn >> 10, n = bn & 1023;
  const float* p = xu + (long long)b * CE * NI + n;
  float s = 0.f;
#pragma unroll 8
  for (int c = 0; c < CE; c++) { float v = p[(long long)c * NI]; s = fmaf(v, v, s); }
  sq[bn] = s;
}

// W[b,i,j] = exp(exp(-d2/128) + (i==j) - 2), d2 = max(sq_i+sq_j-2*dot,0); Zgl += rowsums
__global__ __launch_bounds__(256) void gram_gl(const float* __restrict__ xu,
                                               const float* __restrict__ sqv,
                                               float* __restrict__ W,
                                               float* __restrict__ Z)
{
  __shared__ float Us[64][64];
  __shared__ float Vs[64][64];
  __shared__ float partial[64][16];
  const int b = blockIdx.z;
  const int j0 = blockIdx.x * 64;
  const int i0 = blockIdx.y * 64;
  const float* X = xu + (long long)b * CE * NI;
  const int tid = threadIdx.x;
  const int tx = tid & 15, ty = tid >> 4;
#pragma unroll
  for (int p = 0; p < 4; p++) {
    const int c = p * 16 + (tid >> 4);
    const int col = (tid & 15) << 2;
    *(float4*)&Us[c][col] = *(const float4*)(X + (long long)c * NI + i0 + col);
    *(float4*)&Vs[c][col] = *(const float4*)(X + (long long)c * NI + j0 + col);
  }
  __syncthreads();
  float acc[4][4] = {};
#pragma unroll 8
  for (int c = 0; c < 64; c++) {
    float4 u = *(const float4*)&Us[c][ty << 2];
    float4 v = *(const float4*)&Vs[c][tx << 2];
    float u4[4] = {u.x, u.y, u.z, u.w};
    float v4[4] = {v.x, v.y, v.z, v.w};
#pragma unroll
    for (int i = 0; i < 4; i++)
#pragma unroll
      for (int j = 0; j < 4; j++)
        acc[i][j] = fmaf(u4[i], v4[j], acc[i][j]);
  }
  float sqi[4], sqj[4];
#pragma unroll
  for (int i = 0; i < 4; i++) sqi[i] = sqv[b * NI + i0 + (ty << 2) + i];
#pragma unroll
  for (int j = 0; j < 4; j++) sqj[j] = sqv[b * NI + j0 + (tx << 2) + j];
  float rs[4] = {0.f, 0.f, 0.f, 0.f};
#pragma unroll
  for (int i = 0; i < 4; i++) {
    const int gi = i0 + (ty << 2) + i;
    float4 wout;
    float wv[4];
#pragma unroll
    for (int j = 0; j < 4; j++) {
      const int gj = j0 + (tx << 2) + j;
      float d2 = fmaxf(sqi[i] + sqj[j] - 2.f * acc[i][j], 0.f);
      float w = __expf(__expf(-d2 * (1.f / 128.f)) + (gi == gj ? 1.f : 0.f) - 2.f);
      wv[j] = w;
      rs[i] += w;
    }
    wout.x = wv[0]; wout.y = wv[1]; wout.z = wv[2]; wout.w = wv[3];
    *(float4*)(W + (long long)b * NN2 + (long long)gi * NI + j0 + (tx << 2)) = wout;
  }
#pragma unroll
  for (int i = 0; i < 4; i++) partial[(ty << 2) + i][tx] = rs[i];
  __syncthreads();
  if (tid < 64) {
    float s = 0.f;
#pragma unroll
    for (int t = 0; t < 16; t++) s += partial[tid][t];
    atomicAdd(&Z[b * NI + i0 + tid], s);
  }
}

// Pscaled[b,o,n] = P[b,o,n] / Zgl[b,n]
__global__ __launch_bounds__(256) void pscale_kernel(const float* __restrict__ P,
                                                     const float* __restrict__ Z,
                                                     float* __restrict__ Ps)
{
  const long long idx = (long long)blockIdx.x * 256 + threadIdx.x;  // B2CN total
  const int n = (int)(idx & 1023);
  const int b = (int)(idx >> 17);  // 2*64*1024 per batch
  Ps[idx] = P[idx] / Z[b * NI + n];
}

// LayerNorm over [CE,NI] per (batch, half); half 1 also applies exact GELU
__global__ __launch_bounds__(256) void ln_kernel(const float* __restrict__ T,
                                                 const float* __restrict__ lnw,
                                                 const float* __restrict__ lnb,
                                                 float* __restrict__ xnew,
                                                 float* __restrict__ ftb)
{
  const int b = blockIdx.x;
  const int half = blockIdx.y;
  const float* z = T + (long long)b * S2 + (long long)half * S1;
  float s = 0.f, ss = 0.f;
  for (int i = threadIdx.x; i < (int)S1; i += 256) {
    float v = z[i];
    s += v;
    ss = fmaf(v, v, ss);
  }
  __shared__ float r1[256], r2[256];
  r1[threadIdx.x] = s; r2[threadIdx.x] = ss; __syncthreads();
  for (int st = 128; st > 0; st >>= 1) {
    if (threadIdx.x < st) {
      r1[threadIdx.x] += r1[threadIdx.x + st];
      r2[threadIdx.x] += r2[threadIdx.x + st];
    }
    __syncthreads();
  }
  const float inv_n = 1.f / (float)S1;
  const float mean = r1[0] * inv_n;
  const float var = fmaxf(r2[0] * inv_n - mean * mean, 0.f);
  const float rstd = rsqrtf(var + 1e-5f);
  float* outp = (half ? ftb : xnew) + (long long)b * S1;
  for (int i = threadIdx.x; i < (int)S1; i += 256) {
    float v = (z[i] - mean) * rstd * lnw[i] + lnb[i];
    if (half) v = 0.5f * v * (1.f + erff(v * 0.70710678118654752f));
    outp[i] = v;
  }
}

// ct_new = xn + ft*(ct-xn);  ht = xu + ft*(elu(ct_new)-xu)
__global__ __launch_bounds__(256) void final_kernel(const float* __restrict__ xnew,
                                                    const float* __restrict__ ftb,
                                                    const float* __restrict__ ct,
                                                    const float* __restrict__ xu,
                                                    float* __restrict__ outp)
{
  const long long idx = (long long)blockIdx.x * 256 + threadIdx.x;  // BCN total
  const float ft = ftb[idx];
  const float xn = xnew[idx];
  const float cn = fmaf(ft, ct[idx] - xn, xn);
  const float el = cn > 0.f ? cn : expm1f(cn);
  const float u = xu[idx];
  outp[idx] = fmaf(ft, el - u, u);
  outp[BCN + idx] = cn;
}

extern "C" void kernel_launch(void* const* d_in, const int* in_sizes, int n_in,
                              void* d_out, int out_size, void* d_ws, size_t ws_size,
                              hipStream_t stream)
{
  (void)in_sizes; (void)n_in; (void)out_size; (void)ws_size;
  const float* x      = (const float*)d_in[0];
  const float* ct     = (const float*)d_in[1];
  const float* gdata  = (const float*)d_in[2];
  const float* emb_w  = (const float*)d_in[3];
  const float* emb_b  = (const float*)d_in[4];
  const float* emb2_w = (const float*)d_in[5];
  const float* emb2_b = (const float*)d_in[6];
  const float* att_W  = (const float*)d_in[7];
  const float* att_a  = (const float*)d_in[8];
  // d_in[9] att_GL: unused — softmax(relu(GL GL^T)) is strictly positive, so the
  // where(adj>0, e, NEG) mask is provably a no-op.
  const float* uai_w  = (const float*)d_in[10];
  const float* uai_b  = (const float*)d_in[11];
  const float* lin1_w = (const float*)d_in[12];
  const float* lin2_w = (const float*)d_in[13];
  const float* lin2_b = (const float*)d_in[14];
  const float* ln_w   = (const float*)d_in[15];
  const float* ln_b   = (const float*)d_in[16];
  float* outp = (float*)d_out;

  float* ws = (float*)d_ws;
  long long o = 0;
  auto alloc = [&](long long n) { float* p = ws + o; o += (n + 63) & ~63LL; return p; };
  float* e2t    = alloc(NN2);   // emb2_w transposed
  float* h0a    = alloc(BCN);   // lrelu(conv) result
  float* h0     = alloc(BCN);   // after node-linear
  float* hbuf   = alloc(BCN);   // attention h, [B,N,64]
  float* xattT  = alloc(BCN);   // relu(att@h), [B,N,64]
  float* xuai   = alloc(BCN);   // x_uai, [B,64,N] (kept until final)
  float* g1     = alloc(NN2);
  float* g2     = alloc(NN2);
  float* P      = alloc(B2CN);  // [l1(u); l2(u)]
  float* Psc    = alloc(B2CN);  // P / Zgl (per column n)
  float* Tacc   = alloc(B2CN);  // P@gl then += Q@g2
  float* Tg1    = alloc(B2CN);  // P@g1
  float* Q      = alloc(B2CN);  // [l1(top); l2(bot)]
  float* xnew   = alloc(BCN);
  float* ftb    = alloc(BCN);
  float* bigW   = alloc(BNN);   // 64MB: att p matrix, then gl unnormalized weights
  float* s1     = alloc(BNv);
  float* s2     = alloc(BNv);
  float* s2m    = alloc(BATCH);
  float* Zatt   = alloc(BNv);
  float* Zgl    = alloc(BNv);
  float* sqv    = alloc(BNv);
  float* dsum   = alloc(2 * NI);
  float* stackW = alloc(128 * 64);
  float* rb128  = alloc(128);

  hipMemsetAsync(Zgl, 0, BNv * sizeof(float), stream);

  // ---- prep ----
  transpose_k<<<dim3(NI / 32, NI / 32), dim3(32, 8), 0, stream>>>(emb2_w, e2t);
  pack_kernel<<<32, 256, 0, stream>>>(lin1_w, lin2_w, lin2_b, stackW, rb128);
  lap_rowsum<<<2 * NI, 256, 0, stream>>>(gdata, dsum);
  lap_build<<<dim3(NI / 32, NI / 32, 2), dim3(32, 8), 0, stream>>>(gdata, dsum, g1, g2);

  // ---- embedding ----
  conv_emb<<<BATCH * CE, 256, 0, stream>>>(x, emb_w, emb_b, h0a);
  // h0 = h0a @ emb2_w^T + emb2_b   (rows = b*64+e, K=N, M=N)
  gemm64<<<dim3(16, 16, 1), 256, 0, stream>>>(h0a, e2t, h0, emb2_b, nullptr,
                                              nullptr, 0, NI, NI, 0, 0, 0, 0);

  // ---- attention ----
  h_s_kernel<<<(int)(BNv / 4), 256, 0, stream>>>(h0, att_W, att_a, hbuf, s1, s2);
  s2max_kernel<<<BATCH, 256, 0, stream>>>(s2, s2m);
  att_p<<<dim3(NI, BATCH), 256, 0, stream>>>(s1, s2, s2m, bigW, Zatt);
  // x_attT = relu((p @ h) / Z)
  gemm64<<<dim3(1, 16, BATCH), 256, 0, stream>>>(bigW, hbuf, xattT, nullptr, nullptr,
                                                 Zatt, NI, NI, CE, NN2, S1, S1, GF_RELU);

  // ---- UAI: x_uai = uai_w @ x_att + uai_b  (TRANSB: x_attT is [N,64]) ----
  gemm64<<<dim3(16, 1, BATCH), 256, 0, stream>>>(uai_w, xattT, xuai, nullptr, uai_b,
                                                 nullptr, 0, CE, NI, 0, S1, S1, GF_TRANSB);

  // ---- learned adjacency (unnormalized, Z folded into P columns) ----
  sq_kernel<<<(int)(BNv / 256), 256, 0, stream>>>(xuai, sqv);
  gram_gl<<<dim3(16, 16, BATCH), 256, 0, stream>>>(xuai, sqv, bigW, Zgl);

  // ---- P = [lin1_w @ u ; lin2_w @ u + lin2_b] ----
  gemm64<<<dim3(16, 2, BATCH), 256, 0, stream>>>(stackW, xuai, P, nullptr, rb128,
                                                 nullptr, 0, CE, NI, 0, S1, S2, 0);
  pscale_kernel<<<(int)(B2CN / 256), 256, 0, stream>>>(P, Zgl, Psc);

  // ---- big per-batch matmuls ----
  gemm64<<<dim3(16, 2, BATCH), 256, 0, stream>>>(Psc, bigW, Tacc, nullptr, nullptr,
                                                 nullptr, 0, NI, NI, S2, NN2, S2, 0);
  gemm64<<<dim3(16, 2, BATCH), 256, 0, stream>>>(P, g1, Tg1, nullptr, nullptr,
                                                 nullptr, 0, NI, NI, S2, 0, S2, 0);
  // Q = [lin1_w @ Tg1_top ; lin2_w @ Tg1_bot + lin2_b]
  gemm64<<<dim3(16, 1, BATCH), 256, 0, stream>>>(lin1_w, Tg1, Q, nullptr, nullptr,
                                                 nullptr, 0, CE, NI, 0, S2, S2, 0);
  gemm64<<<dim3(16, 1, BATCH), 256, 0, stream>>>(lin2_w, Tg1 + S1, Q + S1, nullptr,
                                                 lin2_b, nullptr, 0, CE, NI, 0, S2, S2, 0);
  gemm64<<<dim3(16, 2, BATCH), 256, 0, stream>>>(Q, g2, Tacc, nullptr, nullptr,
                                                 nullptr, 0, NI, NI, S2, 0, S2, GF_ACCUM);

  // ---- layernorm (+gelu for ft half) and final gating ----
  ln_kernel<<<dim3(BATCH, 2), 256, 0, stream>>>(Tacc, ln_w, ln_b, xnew, ftb);
  final_kernel<<<(int)(BCN / 256), 256, 0, stream>>>(xnew, ftb, ct, xuai, outp);
}

// Round 2
// 416.213 us; speedup vs baseline: 1.7696x; 1.7696x over previous
//
#include <hip/hip_runtime.h>
#include <math.h>

typedef unsigned short u16;
typedef __attribute__((ext_vector_type(8))) short short8;
typedef __attribute__((ext_vector_type(4))) float floatx4;

constexpr int BATCH = 16;
constexpr int NI = 1024;
constexpr int CE = 64;
constexpr int CI = 16;
constexpr long long NN2  = (long long)NI * NI;          // 1M
constexpr long long BCN  = (long long)BATCH * CE * NI;  // 1M
constexpr long long BNv  = (long long)BATCH * NI;       // 16K
constexpr long long BNN  = (long long)BATCH * NI * NI;  // 16M
constexpr long long S1 = (long long)CE * NI;            // 65536
constexpr long long S2 = 2 * S1;                        // 131072

__device__ __forceinline__ float lrelu01(float x) { return x > 0.f ? x : 0.01f * x; }

__device__ __forceinline__ u16 f2bf(float f) {
  unsigned u = __builtin_bit_cast(unsigned, f);
  return (u16)((u + 0x7fffu + ((u >> 16) & 1u)) >> 16);  // RNE
}
__device__ __forceinline__ float bf2f(u16 h) {
  unsigned u = ((unsigned)h) << 16;
  return __builtin_bit_cast(float, u);
}

// ================= MFMA TN GEMM: C[r][m] = sum_k A[r][k] * Bt[m][k] ==============
// A, Bt bf16 row-major K-contiguous. BK=64, XOR-swizzled 16B chunks in LDS.
// 4 waves 2x2; wave tile (BM/2)x(BN/2); 16x16x32 MFMAs.
// Fragment layouts (m89/m91/m120-verified): A[m=lane&15][k=quad*8+j],
// B[k=quad*8+j][n=lane&15], C/D col=lane&15, row=quad*4+reg.
template<int BM, int BN, int MODE>
__global__ __launch_bounds__(256) void mgemm(
    const u16* __restrict__ Ag, const u16* __restrict__ B1g, const u16* __restrict__ B2g,
    int K1, int K, int lda, int ldb, long long bsA, long long bsB1,
    float* __restrict__ Cf, u16* __restrict__ Cb, int ldc, long long bsC,
    const float* __restrict__ aux1, const float* __restrict__ aux2,
    const float* __restrict__ aux3, const float* __restrict__ aux4,
    float* __restrict__ Zout)
{
  constexpr int RM = BM / 2, RN = BN / 2, MI = RM / 16, NJ = RN / 16;
  __shared__ __align__(16) u16 As[BM * 64];
  __shared__ __align__(16) u16 Bs[BN * 64];
  const int z = blockIdx.z;
  const int n0 = blockIdx.x * BN;
  const int r0 = blockIdx.y * BM;
  const u16* Ab = Ag + (long long)z * bsA + (long long)r0 * lda;
  const u16* Bb1 = B1g + (long long)z * bsB1 + (long long)n0 * ldb;
  const int tid = threadIdx.x;
  const int lane = tid & 63, wid = tid >> 6;
  const int wr = wid >> 1, wc = wid & 1;
  const int q = lane >> 4, mlow = lane & 15;

  floatx4 acc[MI][NJ] = {};

  for (int k0 = 0; k0 < K; k0 += 64) {
    const u16* Asrc = Ab + k0;
    const u16* Bsrc = (k0 < K1) ? (Bb1 + k0)
                                : (B2g + (long long)n0 * ldb + (k0 - K1));
#pragma unroll
    for (int s = 0; s < (BM * 8) / 256; s++) {
      int cid = tid + s * 256;
      int r = cid >> 3, craw = cid & 7;
      uint4 v = *(const uint4*)(Asrc + (long long)r * lda + craw * 8);
      *(uint4*)&As[(r * 8 + (craw ^ (r & 7))) * 8] = v;
    }
#pragma unroll
    for (int s = 0; s < (BN * 8) / 256; s++) {
      int cid = tid + s * 256;
      int r = cid >> 3, craw = cid & 7;
      uint4 v = *(const uint4*)(Bsrc + (long long)r * ldb + craw * 8);
      *(uint4*)&Bs[(r * 8 + (craw ^ (r & 7))) * 8] = v;
    }
    __syncthreads();
#pragma unroll
    for (int kh = 0; kh < 2; kh++) {
      const int kc = kh * 4 + q;
      short8 afr[MI], bfr[NJ];
#pragma unroll
      for (int i = 0; i < MI; i++) {
        int row = wr * RM + i * 16 + mlow;
        afr[i] = *(const short8*)&As[(row * 8 + (kc ^ (row & 7))) * 8];
      }
#pragma unroll
      for (int j = 0; j < NJ; j++) {
        int row = wc * RN + j * 16 + mlow;
        bfr[j] = *(const short8*)&Bs[(row * 8 + (kc ^ (row & 7))) * 8];
      }
#pragma unroll
      for (int i = 0; i < MI; i++)
#pragma unroll
        for (int j = 0; j < NJ; j++)
          acc[i][j] = __builtin_amdgcn_mfma_f32_16x16x32_bf16(afr[i], bfr[j], acc[i][j], 0, 0, 0);
    }
    __syncthreads();
  }

  if constexpr (MODE == 3) {
    const float* sqb = aux1 + (long long)z * NI;
#pragma unroll
    for (int i = 0; i < MI; i++) {
#pragma unroll
      for (int rg = 0; rg < 4; rg++) {
        int r = r0 + wr * RM + i * 16 + q * 4 + rg;
        float sqi = sqb[r];
        float rsum = 0.f;
#pragma unroll
        for (int j = 0; j < NJ; j++) {
          int ncol = n0 + wc * RN + j * 16 + mlow;
          float d2 = fmaxf(sqi + sqb[ncol] - 2.f * acc[i][j][rg], 0.f);
          float w = __expf(__expf(-d2 * (1.f / 128.f)) + (r == ncol ? 1.f : 0.f) - 2.f);
          Cb[(long long)z * bsC + (long long)r * ldc + ncol] = f2bf(w);
          rsum += w;
        }
        rsum += __shfl_xor(rsum, 1);
        rsum += __shfl_xor(rsum, 2);
        rsum += __shfl_xor(rsum, 4);
        rsum += __shfl_xor(rsum, 8);
        if (mlow == 0) atomicAdd(&Zout[(long long)z * NI + r], rsum);
      }
    }
  } else {
#pragma unroll
    for (int i = 0; i < MI; i++) {
#pragma unroll
      for (int j = 0; j < NJ; j++) {
#pragma unroll
        for (int rg = 0; rg < 4; rg++) {
          int r = r0 + wr * RM + i * 16 + q * 4 + rg;
          int ncol = n0 + wc * RN + j * 16 + mlow;
          float v = acc[i][j][rg];
          if constexpr (MODE == 0) {
            v += aux1[ncol];
            Cf[(long long)z * bsC + (long long)r * ldc + ncol] = v;
          } else if constexpr (MODE == 1) {
            v *= aux1[(long long)z * NI + r];
            v = fmaxf(v, 0.f);
            Cb[(long long)z * bsC + (long long)r * ldc + ncol] = f2bf(v);
          } else if constexpr (MODE == 2) {
            v += aux1[ncol];
            long long ix = (long long)z * bsC + (long long)r * ldc + ncol;
            Cf[ix] = v;
            Cb[ix] = f2bf(v);
          } else if constexpr (MODE == 4) {
            int blk = r >> 6, oo = r & 63;
            int drow = ((blk & 1) << 6) + oo;
            float sc = (blk < 2) ? aux1[(long long)z * NI + ncol] : 1.f;
            Cb[(long long)z * bsC + (long long)drow * 2048 + (long long)(blk >> 1) * 1024 + ncol] =
                f2bf(v * sc);
          } else if constexpr (MODE == 5) {
            v += aux3[r] * aux1[(long long)z * NI + ncol] + aux4[r] * aux2[ncol];
            Cf[(long long)z * bsC + (long long)r * ldc + ncol] = v;
          } else if constexpr (MODE == 6) {
            Cb[(long long)z * bsC + (long long)r * ldc + ncol] = f2bf(v);
          }
        }
      }
    }
  }
}

// ---------- prep: stack4=[L1;L2;L1L1;L2L2] bf16, rb2ext, rl2ext, uai_w bf16 ----------
__global__ __launch_bounds__(256) void prep_small(
    const float* __restrict__ l1w, const float* __restrict__ l2w,
    const float* __restrict__ l2b, const float* __restrict__ uaiw,
    u16* __restrict__ stack4, float* __restrict__ rb2ext, float* __restrict__ rl2ext,
    u16* __restrict__ uaiw_bf)
{
  const int gid = blockIdx.x * 256 + threadIdx.x;
  if (gid < 4096) {
    stack4[gid] = f2bf(l1w[gid]);
  } else if (gid < 8192) {
    stack4[gid] = f2bf(l2w[gid - 4096]);
  } else if (gid < 12288) {
    int t = gid - 8192, o = t >> 6, m = t & 63;
    float s = 0.f;
    for (int c = 0; c < 64; c++) s = fmaf(l1w[o * 64 + c], l1w[c * 64 + m], s);
    stack4[gid] = f2bf(s);
  } else if (gid < 16384) {
    int t = gid - 12288, o = t >> 6, m = t & 63;
    float s = 0.f;
    for (int c = 0; c < 64; c++) s = fmaf(l2w[o * 64 + c], l2w[c * 64 + m], s);
    stack4[gid] = f2bf(s);
  } else if (gid < 16512) {
    int r = gid - 16384;
    rb2ext[r] = (r < 64) ? 0.f : l2b[r - 64];
  } else if (gid < 16640) {
    int r = gid - 16512;
    float v = 0.f;
    if (r >= 64) { int o = r - 64; for (int c = 0; c < 64; c++) v = fmaf(l2w[o * 64 + c], l2b[c], v); }
    rl2ext[r] = v;
  } else if (gid < 20736) {
    uaiw_bf[gid - 16640] = f2bf(uaiw[gid - 16640]);
  }
}

__global__ __launch_bounds__(256) void cast_bf(const float* __restrict__ in,
                                               u16* __restrict__ out, int n)
{
  int i = blockIdx.x * 256 + threadIdx.x;
  if (i < n) out[i] = f2bf(in[i]);
}

__global__ __launch_bounds__(256) void lap_rowsum(const float* __restrict__ gd,
                                                  float* __restrict__ dr)
{
  const int ki = blockIdx.x;
  const float* row = gd + (long long)ki * NI;
  float s = 0.f;
  for (int j = threadIdx.x; j < NI; j += 256) s += row[j];
  __shared__ float red[256];
  red[threadIdx.x] = s; __syncthreads();
  for (int st = 128; st > 0; st >>= 1) {
    if (threadIdx.x < st) red[threadIdx.x] += red[threadIdx.x + st];
    __syncthreads();
  }
  if (threadIdx.x == 0) dr[ki] = rsqrtf(red[0] + 1.f);
}

__global__ __launch_bounds__(256) void cs1_kernel(const float* __restrict__ gd0,
                                                  const float* __restrict__ d,
                                                  float* __restrict__ cs1)
{
  const int n = blockIdx.x;
  float s = 0.f;
  for (int i = threadIdx.x; i < NI; i += 256) s = fmaf(gd0[(long long)n * NI + i], d[i], s);
  __shared__ float red[256];
  red[threadIdx.x] = s; __syncthreads();
  for (int st = 128; st > 0; st >>= 1) {
    if (threadIdx.x < st) red[threadIdx.x] += red[threadIdx.x + st];
    __syncthreads();
  }
  if (threadIdx.x == 0) cs1[n] = d[n] * (red[0] + d[n]);
}

__global__ __launch_bounds__(256) void csv2_kernel(const float* __restrict__ gd1,
                                                   const float* __restrict__ d,
                                                   const float* __restrict__ cs1,
                                                   float* __restrict__ cs2,
                                                   float* __restrict__ v2)
{
  const int m = blockIdx.x;
  float s = 0.f, sv = 0.f;
  for (int n = threadIdx.x; n < NI; n += 256) {
    float g = gd1[(long long)m * NI + n] * d[n];
    s += g;
    sv = fmaf(g, cs1[n], sv);
  }
  __shared__ float r1[256], r2[256];
  r1[threadIdx.x] = s; r2[threadIdx.x] = sv; __syncthreads();
  for (int st = 128; st > 0; st >>= 1) {
    if (threadIdx.x < st) { r1[threadIdx.x] += r1[threadIdx.x + st]; r2[threadIdx.x] += r2[threadIdx.x + st]; }
    __syncthreads();
  }
  if (threadIdx.x == 0) {
    cs2[m] = d[m] * (r1[0] + d[m]);
    v2[m] = d[m] * (r2[0] + d[m] * cs1[m]);
  }
}

__global__ __launch_bounds__(256) void g_direct(const float* __restrict__ gd1,
                                                const float* __restrict__ d,
                                                u16* __restrict__ g2t)
{
  long long idx = (long long)blockIdx.x * 256 + threadIdx.x;
  int m = (int)(idx >> 10), j = (int)(idx & 1023);
  float v = (gd1[idx] + (m == j ? 1.f : 0.f)) * d[m] * d[j];
  g2t[idx] = f2bf(v);
}

__global__ __launch_bounds__(256) void g_trans(const float* __restrict__ gd0,
                                               const float* __restrict__ d,
                                               u16* __restrict__ g1)
{
  __shared__ float t[32][33];
  const int bx = blockIdx.x * 32, by = blockIdx.y * 32;
  const int lx = threadIdx.x & 31, ly = threadIdx.x >> 5;  // 32x8
  for (int yy = ly; yy < 32; yy += 8)
    t[yy][lx] = gd0[(long long)(by + yy) * NI + bx + lx];
  __syncthreads();
  for (int yy = ly; yy < 32; yy += 8) {
    const int i = bx + yy, j = by + lx;
    float v = (t[lx][yy] + (i == j ? 1.f : 0.f)) * d[i] * d[j];
    g1[(long long)i * NI + j] = f2bf(v);
  }
}

__global__ __launch_bounds__(256) void conv_emb(const float* __restrict__ x,
                                                const float* __restrict__ ew,
                                                const float* __restrict__ eb,
                                                u16* __restrict__ h0a)
{
  const int be = blockIdx.x;
  const int b = be >> 6, e = be & 63;
  __shared__ float w[CI];
  if (threadIdx.x < CI) w[threadIdx.x] = ew[e * CI + threadIdx.x];
  __syncthreads();
  const float bias = eb[e];
  const float* xb = x + (long long)b * CI * NI;
  u16* outp = h0a + (long long)be * NI;
  for (int n = threadIdx.x; n < NI; n += 256) {
    float a = bias;
#pragma unroll
    for (int c = 0; c < CI; c++) a = fmaf(xb[c * NI + n], w[c], a);
    outp[n] = f2bf(lrelu01(a));
  }
}

__global__ __launch_bounds__(256) void hT_kernel(const float* __restrict__ h0,
                                                 const float* __restrict__ attW,
                                                 const float* __restrict__ atta,
                                                 u16* __restrict__ hTb,
                                                 float* __restrict__ s1,
                                                 float* __restrict__ s2)
{
  __shared__ float w[64 * 64];
  for (int t = threadIdx.x; t < 4096; t += 256) w[t] = attW[t];
  __syncthreads();
  const int b = blockIdx.y;
  const int wid = threadIdx.x >> 6, lane = threadIdx.x & 63;
  const int n0 = blockIdx.x * 16 + wid * 4;
  const float* h0b = h0 + (long long)b * S1;
  float a0 = 0, a1 = 0, a2 = 0, a3 = 0;
  for (int e = 0; e < 64; e++) {
    float4 hv = *(const float4*)(h0b + e * NI + n0);
    float we = w[e * 64 + lane];
    a0 = fmaf(hv.x, we, a0); a1 = fmaf(hv.y, we, a1);
    a2 = fmaf(hv.z, we, a2); a3 = fmaf(hv.w, we, a3);
  }
  unsigned lo = (unsigned)f2bf(a0) | ((unsigned)f2bf(a1) << 16);
  unsigned hi = (unsigned)f2bf(a2) | ((unsigned)f2bf(a3) << 16);
  uint2 pk; pk.x = lo; pk.y = hi;
  *(uint2*)(hTb + (long long)b * S1 + (long long)lane * NI + n0) = pk;
  const float p1 = atta[lane], p2 = atta[64 + lane];
  float av[4] = {a0, a1, a2, a3};
#pragma unroll
  for (int j = 0; j < 4; j++) {
    float v1 = av[j] * p1, v2 = av[j] * p2;
    for (int off = 1; off < 64; off <<= 1) { v1 += __shfl_xor(v1, off); v2 += __shfl_xor(v2, off); }
    if (lane == j) { s1[(long long)b * NI + n0 + j] = v1; s2[(long long)b * NI + n0 + j] = v2; }
  }
}

__global__ __launch_bounds__(256) void s2max_kernel(const float* __restrict__ s2,
                                                    float* __restrict__ s2m)
{
  const int b = blockIdx.x;
  float m = -3.4e38f;
  for (int n = threadIdx.x; n < NI; n += 256) m = fmaxf(m, s2[b * NI + n]);
  __shared__ float red[256];
  red[threadIdx.x] = m; __syncthreads();
  for (int st = 128; st > 0; st >>= 1) {
    if (threadIdx.x < st) red[threadIdx.x] = fmaxf(red[threadIdx.x], red[threadIdx.x + st]);
    __syncthreads();
  }
  if (threadIdx.x == 0) s2m[b] = red[0];
}

__global__ __launch_bounds__(256) void att_p(const float* __restrict__ s1,
                                             const float* __restrict__ s2,
                                             const float* __restrict__ s2m,
                                             u16* __restrict__ Wp,
                                             float* __restrict__ invZatt)
{
  const int i = blockIdx.x;
  const int b = blockIdx.y;
  const float s1i = s1[b * NI + i];
  const float m = lrelu01(s1i + s2m[b]);
  const float* s2b = s2 + b * NI;
  u16* row = Wp + (long long)b * NN2 + (long long)i * NI;
  float lsum = 0.f;
  for (int j = threadIdx.x; j < NI; j += 256) {
    float p = __expf(lrelu01(s1i + s2b[j]) - m);
    row[j] = f2bf(p);
    lsum += p;
  }
  __shared__ float red[256];
  red[threadIdx.x] = lsum; __syncthreads();
  for (int st = 128; st > 0; st >>= 1) {
    if (threadIdx.x < st) red[threadIdx.x] += red[threadIdx.x + st];
    __syncthreads();
  }
  if (threadIdx.x == 0) invZatt[b * NI + i] = 1.f / red[0];
}

__global__ __launch_bounds__(256) void sq_kernel(const u16* __restrict__ xb,
                                                 float* __restrict__ sq)
{
  const int wid = threadIdx.x >> 6, lane = threadIdx.x & 63;
  long long bn = (long long)blockIdx.x * 4 + wid;
  float v = bf2f(xb[bn * 64 + lane]);
  float s = v * v;
  for (int off = 1; off < 64; off <<= 1) s += __shfl_xor(s, off);
  if (lane == 0) sq[bn] = s;
}

__global__ __launch_bounds__(256) void invz_kernel(const float* __restrict__ z,
                                                   float* __restrict__ iz)
{
  int i = blockIdx.x * 256 + threadIdx.x;
  if (i < (int)BNv) iz[i] = 1.f / z[i];
}

__global__ __launch_bounds__(256) void cc_kernel(const u16* __restrict__ W,
                                                 const float* __restrict__ invZ,
                                                 const float* __restrict__ cs2,
                                                 float* __restrict__ cc)
{
  const int m = blockIdx.x, b = blockIdx.y;
  const u16* row = W + (long long)b * NN2 + (long long)m * NI;
  const float* iz = invZ + (long long)b * NI;
  float s = 0.f;
  for (int i = threadIdx.x; i < NI; i += 256) s = fmaf(bf2f(row[i]), iz[i], s);
  __shared__ float red[256];
  red[threadIdx.x] = s; __syncthreads();
  for (int st = 128; st > 0; st >>= 1) {
    if (threadIdx.x < st) red[threadIdx.x] += red[threadIdx.x + st];
    __syncthreads();
  }
  if (threadIdx.x == 0) cc[(long long)b * NI + m] = red[0] + cs2[m];
}

__global__ __launch_bounds__(256) void ln_kernel(const float* __restrict__ T,
                                                 const float* __restrict__ lnw,
                                                 const float* __restrict__ lnb,
                                                 float* __restrict__ xnew,
                                                 float* __restrict__ ftb)
{
  const int b = blockIdx.x;
  const int half = blockIdx.y;
  const float* z = T + (long long)b * S2 + (long long)half * S1;
  float s = 0.f, ss = 0.f;
  for (int i = threadIdx.x; i < (int)S1; i += 256) {
    float v = z[i];
    s += v;
    ss = fmaf(v, v, ss);
  }
  __shared__ float r1[256], r2[256];
  r1[threadIdx.x] = s; r2[threadIdx.x] = ss; __syncthreads();
  for (int st = 128; st > 0; st >>= 1) {
    if (threadIdx.x < st) {
      r1[threadIdx.x] += r1[threadIdx.x + st];
      r2[threadIdx.x] += r2[threadIdx.x + st];
    }
    __syncthreads();
  }
  const float inv_n = 1.f / (float)S1;
  const float mean = r1[0] * inv_n;
  const float var = fmaxf(r2[0] * inv_n - mean * mean, 0.f);
  const float rstd = rsqrtf(var + 1e-5f);
  float* outp = (half ? ftb : xnew) + (long long)b * S1;
  for (int i = threadIdx.x; i < (int)S1; i += 256) {
    float v = (z[i] - mean) * rstd * lnw[i] + lnb[i];
    if (half) v = 0.5f * v * (1.f + erff(v * 0.70710678118654752f));
    outp[i] = v;
  }
}

__global__ __launch_bounds__(256) void final_kernel(const float* __restrict__ xnew,
                                                    const float* __restrict__ ftb,
                                                    const float* __restrict__ ct,
                                                    const float* __restrict__ xuT,
                                                    float* __restrict__ outp)
{
  const long long idx = (long long)blockIdx.x * 256 + threadIdx.x;  // BCN
  const int n = (int)(idx & 1023);
  const int c = (int)((idx >> 10) & 63);
  const long long b = idx >> 16;
  const float u = xuT[(b << 16) + (long long)n * 64 + c];
  const float ft = ftb[idx];
  const float xn = xnew[idx];
  const float cn = fmaf(ft, ct[idx] - xn, xn);
  const float el = cn > 0.f ? cn : expm1f(cn);
  outp[idx] = fmaf(ft, el - u, u);
  outp[BCN + idx] = cn;
}

extern "C" void kernel_launch(void* const* d_in, const int* in_sizes, int n_in,
                              void* d_out, int out_size, void* d_ws, size_t ws_size,
                              hipStream_t stream)
{
  (void)in_sizes; (void)n_in; (void)out_size; (void)ws_size;
  const float* x      = (const float*)d_in[0];
  const float* ct     = (const float*)d_in[1];
  const float* gdata  = (const float*)d_in[2];
  const float* emb_w  = (const float*)d_in[3];
  const float* emb_b  = (const float*)d_in[4];
  const float* emb2_w = (const float*)d_in[5];
  const float* emb2_b = (const float*)d_in[6];
  const float* att_W  = (const float*)d_in[7];
  const float* att_a  = (const float*)d_in[8];
  // d_in[9] att_GL unused: softmax(relu(GL GL^T)) > 0 everywhere -> mask is a no-op
  const float* uai_w  = (const float*)d_in[10];
  const float* uai_b  = (const float*)d_in[11];
  const float* lin1_w = (const float*)d_in[12];
  const float* lin2_w = (const float*)d_in[13];
  const float* lin2_b = (const float*)d_in[14];
  const float* ln_w   = (const float*)d_in[15];
  const float* ln_b   = (const float*)d_in[16];
  float* outp = (float*)d_out;

  float* ws = (float*)d_ws;
  long long o = 0;
  auto af = [&](long long n) { float* p = ws + o; o += (n + 63) & ~63LL; return p; };
  auto au = [&](long long n) { return (u16*)af((n + 1) / 2); };

  float* h0      = af(S1 * BATCH);
  float* Tacc    = af(S2 * BATCH);
  float* xuaiTf  = af(S1 * BATCH);
  float* xnew    = af(BCN);
  float* ftb     = af(BCN);
  float* s1      = af(BNv);
  float* s2      = af(BNv);
  float* s2m     = af(BATCH);
  float* invZatt = af(BNv);
  float* Zgl     = af(BNv);
  float* invZgl  = af(BNv);
  float* sqv     = af(BNv);
  float* dsum    = af(2 * NI);
  float* cs1v    = af(NI);
  float* cs2v    = af(NI);
  float* v2v     = af(NI);
  float* ccv     = af(BNv);
  float* rb2ext  = af(128);
  float* rl2ext  = af(128);
  u16* emb2w_bf  = au(NN2);
  u16* h0a_bf    = au(S1 * BATCH);
  u16* hTb       = au(S1 * BATCH);
  u16* xattb     = au(S1 * BATCH);
  u16* xuaiTb    = au(S1 * BATCH);
  u16* g1b       = au(NN2);
  u16* g2tb      = au(NN2);
  u16* G12b      = au(NN2);
  u16* Abig      = au((long long)BATCH * 128 * 2048);
  u16* stack4    = au(256 * 64);
  u16* uaiw_bf   = au(CE * CE);
  u16* bigW      = au(BNN);  // 32 MB: att p matrix, then gram W

  hipMemsetAsync(Zgl, 0, BNv * sizeof(float), stream);

  prep_small<<<81, 256, 0, stream>>>(lin1_w, lin2_w, lin2_b, uai_w,
                                     stack4, rb2ext, rl2ext, uaiw_bf);
  cast_bf<<<(int)(NN2 / 256), 256, 0, stream>>>(emb2_w, emb2w_bf, (int)NN2);
  lap_rowsum<<<2 * NI, 256, 0, stream>>>(gdata, dsum);
  cs1_kernel<<<NI, 256, 0, stream>>>(gdata, dsum, cs1v);
  csv2_kernel<<<NI, 256, 0, stream>>>(gdata + NN2, dsum + NI, cs1v, cs2v, v2v);
  g_direct<<<(int)(NN2 / 256), 256, 0, stream>>>(gdata + NN2, dsum + NI, g2tb);
  g_trans<<<dim3(32, 32), 256, 0, stream>>>(gdata, dsum, g1b);
  conv_emb<<<BATCH * CE, 256, 0, stream>>>(x, emb_w, emb_b, h0a_bf);

  // G12t = (g1@g2)^T = TN(A=g2t, Bt=g1)
  mgemm<64, 64, 6><<<dim3(16, 16, 1), 256, 0, stream>>>(
      g2tb, g1b, nullptr, NI, NI, NI, NI, 0, 0,
      nullptr, G12b, NI, 0, nullptr, nullptr, nullptr, nullptr, nullptr);

  // h0 = h0a @ emb2_w^T + emb2_b
  mgemm<64, 64, 0><<<dim3(16, 16, 1), 256, 0, stream>>>(
      h0a_bf, emb2w_bf, nullptr, NI, NI, NI, NI, 0, 0,
      h0, nullptr, NI, 0, emb2_b, nullptr, nullptr, nullptr, nullptr);

  hT_kernel<<<dim3(64, BATCH), 256, 0, stream>>>(h0, att_W, att_a, hTb, s1, s2);
  s2max_kernel<<<BATCH, 256, 0, stream>>>(s2, s2m);
  att_p<<<dim3(NI, BATCH), 256, 0, stream>>>(s1, s2, s2m, bigW, invZatt);

  // x_att = relu((p@h)/Z) -> bf16 [b][n][c]
  mgemm<64, 64, 1><<<dim3(1, 16, BATCH), 256, 0, stream>>>(
      bigW, hTb, nullptr, NI, NI, NI, NI, NN2, S1,
      nullptr, xattb, CE, S1, invZatt, nullptr, nullptr, nullptr, nullptr);

  // x_uaiT = x_att @ uai_w^T + uai_b (dual fp32 + bf16)
  mgemm<64, 64, 2><<<dim3(1, 16, BATCH), 256, 0, stream>>>(
      xattb, uaiw_bf, nullptr, CE, CE, CE, CE, S1, 0,
      xuaiTf, xuaiTb, CE, S1, uai_b, nullptr, nullptr, nullptr, nullptr);

  sq_kernel<<<(int)(BNv / 4), 256, 0, stream>>>(xuaiTb, sqv);
  // gram/gl weights (symmetric, exp(S-2), rowsums into Zgl)
  mgemm<64, 64, 3><<<dim3(16, 16, BATCH), 256, 0, stream>>>(
      xuaiTb, xuaiTb, nullptr, CE, CE, CE, CE, S1, S1,
      nullptr, bigW, NI, NN2, sqv, nullptr, nullptr, nullptr, Zgl);
  invz_kernel<<<64, 256, 0, stream>>>(Zgl, invZgl);
  cc_kernel<<<dim3(NI, BATCH), 256, 0, stream>>>(bigW, invZgl, cs2v, ccv);

  // Abig = [[L1u/Z | L1L1u],[L2u/Z | L2L2u]] bf16
  mgemm<64, 64, 4><<<dim3(16, 4, BATCH), 256, 0, stream>>>(
      stack4, xuaiTb, nullptr, CE, CE, CE, CE, 0, S1,
      nullptr, Abig, 0, (long long)128 * 2048, invZgl, nullptr, nullptr, nullptr, nullptr);

  // fused: Tacc = Abig @ [W ; G12t] + b2 (x) cc + (L2 b2) (x) v2
  mgemm<64, 128, 5><<<dim3(8, 2, BATCH), 256, 0, stream>>>(
      Abig, bigW, G12b, NI, 2 * NI, 2048, NI, (long long)128 * 2048, NN2,
      Tacc, nullptr, NI, S2, ccv, v2v, rb2ext, rl2ext, nullptr);

  ln_kernel<<<dim3(BATCH, 2), 256, 0, stream>>>(Tacc, ln_w, ln_b, xnew, ftb);
  final_kernel<<<(int)(BCN / 256), 256, 0, stream>>>(xnew, ftb, ct, xuaiTf, outp);
}

// Round 3
// 307.460 us; speedup vs baseline: 2.3955x; 1.3537x over previous
//
#include <hip/hip_runtime.h>
#include <math.h>

typedef unsigned short u16;
typedef __attribute__((ext_vector_type(8))) short short8;
typedef __attribute__((ext_vector_type(4))) float floatx4;

constexpr int BATCH = 16;
constexpr int NI = 1024;
constexpr int CE = 64;
constexpr int CI = 16;
constexpr long long NN2  = (long long)NI * NI;          // 1M
constexpr long long BCN  = (long long)BATCH * CE * NI;  // 1M
constexpr long long BNv  = (long long)BATCH * NI;       // 16K
constexpr long long BNN  = (long long)BATCH * NI * NI;  // 16M
constexpr long long S1 = (long long)CE * NI;            // 65536
constexpr long long S2 = 2 * S1;                        // 131072

__device__ __forceinline__ float lrelu01(float x) { return x > 0.f ? x : 0.01f * x; }

__device__ __forceinline__ u16 f2bf(float f) {
  unsigned u = __builtin_bit_cast(unsigned, f);
  return (u16)((u + 0x7fffu + ((u >> 16) & 1u)) >> 16);  // RNE
}
__device__ __forceinline__ float bf2f(u16 h) {
  unsigned u = ((unsigned)h) << 16;
  return __builtin_bit_cast(float, u);
}

// ================= MFMA TN GEMM: C[r][m] = sum_k A[r][k] * Bt[m][k] ==============
// A, Bt bf16 row-major K-contiguous. BK=64, XOR-swizzled 16B chunks in LDS.
// 4 waves 2x2; wave tile (BM/2)x(BN/2); 16x16x32 MFMAs.
template<int BM, int BN, int MODE>
__global__ __launch_bounds__(256) void mgemm(
    const u16* __restrict__ Ag, const u16* __restrict__ B1g, const u16* __restrict__ B2g,
    int K1, int K, int lda, int ldb, long long bsA, long long bsB1,
    float* __restrict__ Cf, u16* __restrict__ Cb, int ldc, long long bsC,
    const float* __restrict__ aux1, const float* __restrict__ aux2,
    const float* __restrict__ aux3, const float* __restrict__ aux4,
    float* __restrict__ Zout)
{
  constexpr int RM = BM / 2, RN = BN / 2, MI = RM / 16, NJ = RN / 16;
  __shared__ __align__(16) u16 As[BM * 64];
  __shared__ __align__(16) u16 Bs[BN * 64];
  const int z = blockIdx.z;
  const int n0 = blockIdx.x * BN;
  const int r0 = blockIdx.y * BM;
  const u16* Ab = Ag + (long long)z * bsA + (long long)r0 * lda;
  const u16* Bb1 = B1g + (long long)z * bsB1 + (long long)n0 * ldb;
  const int tid = threadIdx.x;
  const int lane = tid & 63, wid = tid >> 6;
  const int wr = wid >> 1, wc = wid & 1;
  const int q = lane >> 4, mlow = lane & 15;

  floatx4 acc[MI][NJ] = {};

  for (int k0 = 0; k0 < K; k0 += 64) {
    const u16* Asrc = Ab + k0;
    const u16* Bsrc = (k0 < K1) ? (Bb1 + k0)
                                : (B2g + (long long)n0 * ldb + (k0 - K1));
#pragma unroll
    for (int s = 0; s < (BM * 8) / 256; s++) {
      int cid = tid + s * 256;
      int r = cid >> 3, craw = cid & 7;
      uint4 v = *(const uint4*)(Asrc + (long long)r * lda + craw * 8);
      *(uint4*)&As[(r * 8 + (craw ^ (r & 7))) * 8] = v;
    }
#pragma unroll
    for (int s = 0; s < (BN * 8) / 256; s++) {
      int cid = tid + s * 256;
      int r = cid >> 3, craw = cid & 7;
      uint4 v = *(const uint4*)(Bsrc + (long long)r * ldb + craw * 8);
      *(uint4*)&Bs[(r * 8 + (craw ^ (r & 7))) * 8] = v;
    }
    __syncthreads();
#pragma unroll
    for (int kh = 0; kh < 2; kh++) {
      const int kc = kh * 4 + q;
      short8 afr[MI], bfr[NJ];
#pragma unroll
      for (int i = 0; i < MI; i++) {
        int row = wr * RM + i * 16 + mlow;
        afr[i] = *(const short8*)&As[(row * 8 + (kc ^ (row & 7))) * 8];
      }
#pragma unroll
      for (int j = 0; j < NJ; j++) {
        int row = wc * RN + j * 16 + mlow;
        bfr[j] = *(const short8*)&Bs[(row * 8 + (kc ^ (row & 7))) * 8];
      }
#pragma unroll
      for (int i = 0; i < MI; i++)
#pragma unroll
        for (int j = 0; j < NJ; j++)
          acc[i][j] = __builtin_amdgcn_mfma_f32_16x16x32_bf16(afr[i], bfr[j], acc[i][j], 0, 0, 0);
    }
    __syncthreads();
  }

  if constexpr (MODE == 3) {
    const float* sqb = aux1 + (long long)z * NI;
#pragma unroll
    for (int i = 0; i < MI; i++) {
#pragma unroll
      for (int rg = 0; rg < 4; rg++) {
        int r = r0 + wr * RM + i * 16 + q * 4 + rg;
        float sqi = sqb[r];
        float rsum = 0.f;
#pragma unroll
        for (int j = 0; j < NJ; j++) {
          int ncol = n0 + wc * RN + j * 16 + mlow;
          float d2 = fmaxf(sqi + sqb[ncol] - 2.f * acc[i][j][rg], 0.f);
          float w = __expf(__expf(-d2 * (1.f / 128.f)) + (r == ncol ? 1.f : 0.f) - 2.f);
          Cb[(long long)z * bsC + (long long)r * ldc + ncol] = f2bf(w);
          rsum += w;
        }
        rsum += __shfl_xor(rsum, 1);
        rsum += __shfl_xor(rsum, 2);
        rsum += __shfl_xor(rsum, 4);
        rsum += __shfl_xor(rsum, 8);
        if (mlow == 0) atomicAdd(&Zout[(long long)z * NI + r], rsum);
      }
    }
  } else {
#pragma unroll
    for (int i = 0; i < MI; i++) {
#pragma unroll
      for (int j = 0; j < NJ; j++) {
#pragma unroll
        for (int rg = 0; rg < 4; rg++) {
          int r = r0 + wr * RM + i * 16 + q * 4 + rg;
          int ncol = n0 + wc * RN + j * 16 + mlow;
          float v = acc[i][j][rg];
          if constexpr (MODE == 0) {
            v += aux1[ncol];
            Cf[(long long)z * bsC + (long long)r * ldc + ncol] = v;
          } else if constexpr (MODE == 1) {
            v *= aux1[(long long)z * NI + r];
            v = fmaxf(v, 0.f);
            Cb[(long long)z * bsC + (long long)r * ldc + ncol] = f2bf(v);
          } else if constexpr (MODE == 2) {
            v += aux1[ncol];
            long long ix = (long long)z * bsC + (long long)r * ldc + ncol;
            Cf[ix] = v;
            Cb[ix] = f2bf(v);
          } else if constexpr (MODE == 4) {
            int blk = r >> 6, oo = r & 63;
            int drow = ((blk & 1) << 6) + oo;
            float sc = (blk < 2) ? aux1[(long long)z * NI + ncol] : 1.f;
            Cb[(long long)z * bsC + (long long)drow * 2048 + (long long)(blk >> 1) * 1024 + ncol] =
                f2bf(v * sc);
          } else if constexpr (MODE == 5) {
            v += aux3[r] * aux1[(long long)z * NI + ncol] + aux4[r] * aux2[ncol];
            Cf[(long long)z * bsC + (long long)r * ldc + ncol] = v;
          } else if constexpr (MODE == 6) {
            Cb[(long long)z * bsC + (long long)r * ldc + ncol] = f2bf(v);
          }
        }
      }
    }
  }
}

// ---------- prep: stack4=[L1;L2;L1L1;L2L2] bf16, rb2ext, rl2ext, uai_w bf16 ----------
__global__ __launch_bounds__(256) void prep_small(
    const float* __restrict__ l1w, const float* __restrict__ l2w,
    const float* __restrict__ l2b, const float* __restrict__ uaiw,
    u16* __restrict__ stack4, float* __restrict__ rb2ext, float* __restrict__ rl2ext,
    u16* __restrict__ uaiw_bf)
{
  const int gid = blockIdx.x * 256 + threadIdx.x;
  if (gid < 4096) {
    stack4[gid] = f2bf(l1w[gid]);
  } else if (gid < 8192) {
    stack4[gid] = f2bf(l2w[gid - 4096]);
  } else if (gid < 12288) {
    int t = gid - 8192, o = t >> 6, m = t & 63;
    float s = 0.f;
    for (int c = 0; c < 64; c++) s = fmaf(l1w[o * 64 + c], l1w[c * 64 + m], s);
    stack4[gid] = f2bf(s);
  } else if (gid < 16384) {
    int t = gid - 12288, o = t >> 6, m = t & 63;
    float s = 0.f;
    for (int c = 0; c < 64; c++) s = fmaf(l2w[o * 64 + c], l2w[c * 64 + m], s);
    stack4[gid] = f2bf(s);
  } else if (gid < 16512) {
    int r = gid - 16384;
    rb2ext[r] = (r < 64) ? 0.f : l2b[r - 64];
  } else if (gid < 16640) {
    int r = gid - 16512;
    float v = 0.f;
    if (r >= 64) { int o = r - 64; for (int c = 0; c < 64; c++) v = fmaf(l2w[o * 64 + c], l2b[c], v); }
    rl2ext[r] = v;
  } else if (gid < 20736) {
    uaiw_bf[gid - 16640] = f2bf(uaiw[gid - 16640]);
  }
}

__global__ __launch_bounds__(256) void cast_bf(const float* __restrict__ in,
                                               u16* __restrict__ out, int n)
{
  int i = blockIdx.x * 256 + threadIdx.x;
  if (i < n) out[i] = f2bf(in[i]);
}

__global__ __launch_bounds__(256) void lap_rowsum(const float* __restrict__ gd,
                                                  float* __restrict__ dr)
{
  const int ki = blockIdx.x;
  const float* row = gd + (long long)ki * NI;
  float s = 0.f;
  for (int j = threadIdx.x; j < NI; j += 256) s += row[j];
  __shared__ float red[256];
  red[threadIdx.x] = s; __syncthreads();
  for (int st = 128; st > 0; st >>= 1) {
    if (threadIdx.x < st) red[threadIdx.x] += red[threadIdx.x + st];
    __syncthreads();
  }
  if (threadIdx.x == 0) dr[ki] = rsqrtf(red[0] + 1.f);
}

__global__ __launch_bounds__(256) void cs1_kernel(const float* __restrict__ gd0,
                                                  const float* __restrict__ d,
                                                  float* __restrict__ cs1)
{
  const int n = blockIdx.x;
  float s = 0.f;
  for (int i = threadIdx.x; i < NI; i += 256) s = fmaf(gd0[(long long)n * NI + i], d[i], s);
  __shared__ float red[256];
  red[threadIdx.x] = s; __syncthreads();
  for (int st = 128; st > 0; st >>= 1) {
    if (threadIdx.x < st) red[threadIdx.x] += red[threadIdx.x + st];
    __syncthreads();
  }
  if (threadIdx.x == 0) cs1[n] = d[n] * (red[0] + d[n]);
}

__global__ __launch_bounds__(256) void csv2_kernel(const float* __restrict__ gd1,
                                                   const float* __restrict__ d,
                                                   const float* __restrict__ cs1,
                                                   float* __restrict__ cs2,
                                                   float* __restrict__ v2)
{
  const int m = blockIdx.x;
  float s = 0.f, sv = 0.f;
  for (int n = threadIdx.x; n < NI; n += 256) {
    float g = gd1[(long long)m * NI + n] * d[n];
    s += g;
    sv = fmaf(g, cs1[n], sv);
  }
  __shared__ float r1[256], r2[256];
  r1[threadIdx.x] = s; r2[threadIdx.x] = sv; __syncthreads();
  for (int st = 128; st > 0; st >>= 1) {
    if (threadIdx.x < st) { r1[threadIdx.x] += r1[threadIdx.x + st]; r2[threadIdx.x] += r2[threadIdx.x + st]; }
    __syncthreads();
  }
  if (threadIdx.x == 0) {
    cs2[m] = d[m] * (r1[0] + d[m]);
    v2[m] = d[m] * (r2[0] + d[m] * cs1[m]);
  }
}

__global__ __launch_bounds__(256) void g_direct(const float* __restrict__ gd1,
                                                const float* __restrict__ d,
                                                u16* __restrict__ g2t)
{
  long long idx = (long long)blockIdx.x * 256 + threadIdx.x;
  int m = (int)(idx >> 10), j = (int)(idx & 1023);
  float v = (gd1[idx] + (m == j ? 1.f : 0.f)) * d[m] * d[j];
  g2t[idx] = f2bf(v);
}

__global__ __launch_bounds__(256) void g_trans(const float* __restrict__ gd0,
                                               const float* __restrict__ d,
                                               u16* __restrict__ g1)
{
  __shared__ float t[32][33];
  const int bx = blockIdx.x * 32, by = blockIdx.y * 32;
  const int lx = threadIdx.x & 31, ly = threadIdx.x >> 5;  // 32x8
  for (int yy = ly; yy < 32; yy += 8)
    t[yy][lx] = gd0[(long long)(by + yy) * NI + bx + lx];
  __syncthreads();
  for (int yy = ly; yy < 32; yy += 8) {
    const int i = bx + yy, j = by + lx;
    float v = (t[lx][yy] + (i == j ? 1.f : 0.f)) * d[i] * d[j];
    g1[(long long)i * NI + j] = f2bf(v);
  }
}

__global__ __launch_bounds__(256) void conv_emb(const float* __restrict__ x,
                                                const float* __restrict__ ew,
                                                const float* __restrict__ eb,
                                                u16* __restrict__ h0a)
{
  const int be = blockIdx.x;
  const int b = be >> 6, e = be & 63;
  __shared__ float w[CI];
  if (threadIdx.x < CI) w[threadIdx.x] = ew[e * CI + threadIdx.x];
  __syncthreads();
  const float bias = eb[e];
  const float* xb = x + (long long)b * CI * NI;
  u16* outp = h0a + (long long)be * NI;
  for (int n = threadIdx.x; n < NI; n += 256) {
    float a = bias;
#pragma unroll
    for (int c = 0; c < CI; c++) a = fmaf(xb[c * NI + n], w[c], a);
    outp[n] = f2bf(lrelu01(a));
  }
}

__global__ __launch_bounds__(256) void hT_kernel(const float* __restrict__ h0,
                                                 const float* __restrict__ attW,
                                                 const float* __restrict__ atta,
                                                 u16* __restrict__ hTb,
                                                 float* __restrict__ s1,
                                                 float* __restrict__ s2)
{
  __shared__ float w[64 * 64];
  for (int t = threadIdx.x; t < 4096; t += 256) w[t] = attW[t];
  __syncthreads();
  const int b = blockIdx.y;
  const int wid = threadIdx.x >> 6, lane = threadIdx.x & 63;
  const int n0 = blockIdx.x * 16 + wid * 4;
  const float* h0b = h0 + (long long)b * S1;
  float a0 = 0, a1 = 0, a2 = 0, a3 = 0;
  for (int e = 0; e < 64; e++) {
    float4 hv = *(const float4*)(h0b + e * NI + n0);
    float we = w[e * 64 + lane];
    a0 = fmaf(hv.x, we, a0); a1 = fmaf(hv.y, we, a1);
    a2 = fmaf(hv.z, we, a2); a3 = fmaf(hv.w, we, a3);
  }
  unsigned lo = (unsigned)f2bf(a0) | ((unsigned)f2bf(a1) << 16);
  unsigned hi = (unsigned)f2bf(a2) | ((unsigned)f2bf(a3) << 16);
  uint2 pk; pk.x = lo; pk.y = hi;
  *(uint2*)(hTb + (long long)b * S1 + (long long)lane * NI + n0) = pk;
  const float p1 = atta[lane], p2 = atta[64 + lane];
  float av[4] = {a0, a1, a2, a3};
#pragma unroll
  for (int j = 0; j < 4; j++) {
    float v1 = av[j] * p1, v2 = av[j] * p2;
    for (int off = 1; off < 64; off <<= 1) { v1 += __shfl_xor(v1, off); v2 += __shfl_xor(v2, off); }
    if (lane == j) { s1[(long long)b * NI + n0 + j] = v1; s2[(long long)b * NI + n0 + j] = v2; }
  }
}

__global__ __launch_bounds__(256) void s2max_kernel(const float* __restrict__ s2,
                                                    float* __restrict__ s2m)
{
  const int b = blockIdx.x;
  float m = -3.4e38f;
  for (int n = threadIdx.x; n < NI; n += 256) m = fmaxf(m, s2[b * NI + n]);
  __shared__ float red[256];
  red[threadIdx.x] = m; __syncthreads();
  for (int st = 128; st > 0; st >>= 1) {
    if (threadIdx.x < st) red[threadIdx.x] = fmaxf(red[threadIdx.x], red[threadIdx.x + st]);
    __syncthreads();
  }
  if (threadIdx.x == 0) s2m[b] = red[0];
}

__global__ __launch_bounds__(256) void att_p(const float* __restrict__ s1,
                                             const float* __restrict__ s2,
                                             const float* __restrict__ s2m,
                                             u16* __restrict__ Wp,
                                             float* __restrict__ invZatt)
{
  const int i = blockIdx.x;
  const int b = blockIdx.y;
  const float s1i = s1[b * NI + i];
  const float m = lrelu01(s1i + s2m[b]);
  const float* s2b = s2 + b * NI;
  u16* row = Wp + (long long)b * NN2 + (long long)i * NI;
  float lsum = 0.f;
  for (int j = threadIdx.x; j < NI; j += 256) {
    float p = __expf(lrelu01(s1i + s2b[j]) - m);
    row[j] = f2bf(p);
    lsum += p;
  }
  __shared__ float red[256];
  red[threadIdx.x] = lsum; __syncthreads();
  for (int st = 128; st > 0; st >>= 1) {
    if (threadIdx.x < st) red[threadIdx.x] += red[threadIdx.x + st];
    __syncthreads();
  }
  if (threadIdx.x == 0) invZatt[b * NI + i] = 1.f / red[0];
}

__global__ __launch_bounds__(256) void sq_kernel(const u16* __restrict__ xb,
                                                 float* __restrict__ sq)
{
  const int wid = threadIdx.x >> 6, lane = threadIdx.x & 63;
  long long bn = (long long)blockIdx.x * 4 + wid;
  float v = bf2f(xb[bn * 64 + lane]);
  float s = v * v;
  for (int off = 1; off < 64; off <<= 1) s += __shfl_xor(s, off);
  if (lane == 0) sq[bn] = s;
}

__global__ __launch_bounds__(256) void invz_kernel(const float* __restrict__ z,
                                                   float* __restrict__ iz)
{
  int i = blockIdx.x * 256 + threadIdx.x;
  if (i < (int)BNv) iz[i] = 1.f / z[i];
}

__global__ __launch_bounds__(256) void cc_kernel(const u16* __restrict__ W,
                                                 const float* __restrict__ invZ,
                                                 const float* __restrict__ cs2,
                                                 float* __restrict__ cc)
{
  const int m = blockIdx.x, b = blockIdx.y;
  const u16* row = W + (long long)b * NN2 + (long long)m * NI;
  const float* iz = invZ + (long long)b * NI;
  float s = 0.f;
  for (int i = threadIdx.x; i < NI; i += 256) s = fmaf(bf2f(row[i]), iz[i], s);
  __shared__ float red[256];
  red[threadIdx.x] = s; __syncthreads();
  for (int st = 128; st > 0; st >>= 1) {
    if (threadIdx.x < st) red[threadIdx.x] += red[threadIdx.x + st];
    __syncthreads();
  }
  if (threadIdx.x == 0) cc[(long long)b * NI + m] = red[0] + cs2[m];
}

// ---- LayerNorm phase 1: partial sums over 4096-elem chunks, atomics into stats ----
// stats[0..31] = sum for (b,half); stats[32..63] = sumsq.
__global__ __launch_bounds__(256) void ln_reduce(const float* __restrict__ T,
                                                 float* __restrict__ stats)
{
  const int b = blockIdx.x, half = blockIdx.y, chunk = blockIdx.z;
  const float* z = T + (long long)b * S2 + (long long)half * S1 + (long long)chunk * 4096;
  float s = 0.f, ss = 0.f;
#pragma unroll
  for (int it = 0; it < 4; it++) {
    float4 v = *(const float4*)(z + it * 1024 + threadIdx.x * 4);
    s += v.x + v.y + v.z + v.w;
    ss = fmaf(v.x, v.x, ss); ss = fmaf(v.y, v.y, ss);
    ss = fmaf(v.z, v.z, ss); ss = fmaf(v.w, v.w, ss);
  }
  for (int off = 1; off < 64; off <<= 1) {
    s += __shfl_xor(s, off);
    ss += __shfl_xor(ss, off);
  }
  __shared__ float r1[4], r2[4];
  const int wid = threadIdx.x >> 6, lane = threadIdx.x & 63;
  if (lane == 0) { r1[wid] = s; r2[wid] = ss; }
  __syncthreads();
  if (threadIdx.x == 0) {
    float ts = r1[0] + r1[1] + r1[2] + r1[3];
    float tss = r2[0] + r2[1] + r2[2] + r2[3];
    atomicAdd(&stats[b * 2 + half], ts);
    atomicAdd(&stats[32 + b * 2 + half], tss);
  }
}

// ---- LayerNorm phase 2 fused with GELU + final gating ----
// xn = LN(T_half0); ft = gelu(LN(T_half1));
// ct_new = xn + ft*(ct-xn); ht = xu + ft*(elu(ct_new)-xu)
__global__ __launch_bounds__(256) void ln_final(const float* __restrict__ T,
                                                const float* __restrict__ stats,
                                                const float* __restrict__ lnw,
                                                const float* __restrict__ lnb,
                                                const float* __restrict__ ct,
                                                const float* __restrict__ xuT,
                                                float* __restrict__ outp)
{
  const long long idx = (long long)blockIdx.x * 256 + threadIdx.x;  // BCN
  const long long b = idx >> 16;
  const int rem = (int)(idx & 65535);
  const int n = rem & 1023, c = rem >> 10;
  const float t0 = T[b * S2 + rem];
  const float t1 = T[b * S2 + S1 + rem];
  const float inv_n = 1.f / (float)S1;
  const float m0 = stats[b * 2] * inv_n;
  const float m1 = stats[b * 2 + 1] * inv_n;
  const float v0 = fmaxf(stats[32 + b * 2] * inv_n - m0 * m0, 0.f);
  const float v1 = fmaxf(stats[32 + b * 2 + 1] * inv_n - m1 * m1, 0.f);
  const float rs0 = rsqrtf(v0 + 1e-5f);
  const float rs1 = rsqrtf(v1 + 1e-5f);
  const float w = lnw[rem], bb = lnb[rem];
  const float xn = (t0 - m0) * rs0 * w + bb;
  float ft = (t1 - m1) * rs1 * w + bb;
  ft = 0.5f * ft * (1.f + erff(ft * 0.70710678118654752f));
  const float u = xuT[(b << 16) + (long long)n * 64 + c];
  const float cn = fmaf(ft, ct[idx] - xn, xn);
  const float el = cn > 0.f ? cn : expm1f(cn);
  outp[idx] = fmaf(ft, el - u, u);
  outp[BCN + idx] = cn;
}

extern "C" void kernel_launch(void* const* d_in, const int* in_sizes, int n_in,
                              void* d_out, int out_size, void* d_ws, size_t ws_size,
                              hipStream_t stream)
{
  (void)in_sizes; (void)n_in; (void)out_size; (void)ws_size;
  const float* x      = (const float*)d_in[0];
  const float* ct     = (const float*)d_in[1];
  const float* gdata  = (const float*)d_in[2];
  const float* emb_w  = (const float*)d_in[3];
  const float* emb_b  = (const float*)d_in[4];
  const float* emb2_w = (const float*)d_in[5];
  const float* emb2_b = (const float*)d_in[6];
  const float* att_W  = (const float*)d_in[7];
  const float* att_a  = (const float*)d_in[8];
  // d_in[9] att_GL unused: softmax(relu(GL GL^T)) > 0 everywhere -> mask is a no-op
  const float* uai_w  = (const float*)d_in[10];
  const float* uai_b  = (const float*)d_in[11];
  const float* lin1_w = (const float*)d_in[12];
  const float* lin2_w = (const float*)d_in[13];
  const float* lin2_b = (const float*)d_in[14];
  const float* ln_w   = (const float*)d_in[15];
  const float* ln_b   = (const float*)d_in[16];
  float* outp = (float*)d_out;

  float* ws = (float*)d_ws;
  long long o = 0;
  auto af = [&](long long n) { float* p = ws + o; o += (n + 63) & ~63LL; return p; };
  auto au = [&](long long n) { return (u16*)af((n + 1) / 2); };

  float* h0      = af(S1 * BATCH);
  float* Tacc    = af(S2 * BATCH);
  float* xuaiTf  = af(S1 * BATCH);
  float* s1      = af(BNv);
  float* s2      = af(BNv);
  float* s2m     = af(BATCH);
  float* invZatt = af(BNv);
  float* Zgl     = af(BNv);
  float* invZgl  = af(BNv);
  float* sqv     = af(BNv);
  float* dsum    = af(2 * NI);
  float* cs1v    = af(NI);
  float* cs2v    = af(NI);
  float* v2v     = af(NI);
  float* ccv     = af(BNv);
  float* rb2ext  = af(128);
  float* rl2ext  = af(128);
  float* stats   = af(64);
  u16* emb2w_bf  = au(NN2);
  u16* h0a_bf    = au(S1 * BATCH);
  u16* hTb       = au(S1 * BATCH);
  u16* xattb     = au(S1 * BATCH);
  u16* xuaiTb    = au(S1 * BATCH);
  u16* g1b       = au(NN2);
  u16* g2tb      = au(NN2);
  u16* G12b      = au(NN2);
  u16* Abig      = au((long long)BATCH * 128 * 2048);
  u16* stack4    = au(256 * 64);
  u16* uaiw_bf   = au(CE * CE);
  u16* bigW      = au(BNN);  // 32 MB: att p matrix, then gram W

  hipMemsetAsync(Zgl, 0, BNv * sizeof(float), stream);
  hipMemsetAsync(stats, 0, 64 * sizeof(float), stream);

  prep_small<<<81, 256, 0, stream>>>(lin1_w, lin2_w, lin2_b, uai_w,
                                     stack4, rb2ext, rl2ext, uaiw_bf);
  cast_bf<<<(int)(NN2 / 256), 256, 0, stream>>>(emb2_w, emb2w_bf, (int)NN2);
  lap_rowsum<<<2 * NI, 256, 0, stream>>>(gdata, dsum);
  cs1_kernel<<<NI, 256, 0, stream>>>(gdata, dsum, cs1v);
  csv2_kernel<<<NI, 256, 0, stream>>>(gdata + NN2, dsum + NI, cs1v, cs2v, v2v);
  g_direct<<<(int)(NN2 / 256), 256, 0, stream>>>(gdata + NN2, dsum + NI, g2tb);
  g_trans<<<dim3(32, 32), 256, 0, stream>>>(gdata, dsum, g1b);
  conv_emb<<<BATCH * CE, 256, 0, stream>>>(x, emb_w, emb_b, h0a_bf);

  // G12t = (g1@g2)^T = TN(A=g2t, Bt=g1)
  mgemm<64, 64, 6><<<dim3(16, 16, 1), 256, 0, stream>>>(
      g2tb, g1b, nullptr, NI, NI, NI, NI, 0, 0,
      nullptr, G12b, NI, 0, nullptr, nullptr, nullptr, nullptr, nullptr);

  // h0 = h0a @ emb2_w^T + emb2_b
  mgemm<64, 64, 0><<<dim3(16, 16, 1), 256, 0, stream>>>(
      h0a_bf, emb2w_bf, nullptr, NI, NI, NI, NI, 0, 0,
      h0, nullptr, NI, 0, emb2_b, nullptr, nullptr, nullptr, nullptr);

  hT_kernel<<<dim3(64, BATCH), 256, 0, stream>>>(h0, att_W, att_a, hTb, s1, s2);
  s2max_kernel<<<BATCH, 256, 0, stream>>>(s2, s2m);
  att_p<<<dim3(NI, BATCH), 256, 0, stream>>>(s1, s2, s2m, bigW, invZatt);

  // x_att = relu((p@h)/Z) -> bf16 [b][n][c]
  mgemm<64, 64, 1><<<dim3(1, 16, BATCH), 256, 0, stream>>>(
      bigW, hTb, nullptr, NI, NI, NI, NI, NN2, S1,
      nullptr, xattb, CE, S1, invZatt, nullptr, nullptr, nullptr, nullptr);

  // x_uaiT = x_att @ uai_w^T + uai_b (dual fp32 + bf16)
  mgemm<64, 64, 2><<<dim3(1, 16, BATCH), 256, 0, stream>>>(
      xattb, uaiw_bf, nullptr, CE, CE, CE, CE, S1, 0,
      xuaiTf, xuaiTb, CE, S1, uai_b, nullptr, nullptr, nullptr, nullptr);

  sq_kernel<<<(int)(BNv / 4), 256, 0, stream>>>(xuaiTb, sqv);
  // gram/gl weights (symmetric, exp(S-2), rowsums into Zgl)
  mgemm<64, 64, 3><<<dim3(16, 16, BATCH), 256, 0, stream>>>(
      xuaiTb, xuaiTb, nullptr, CE, CE, CE, CE, S1, S1,
      nullptr, bigW, NI, NN2, sqv, nullptr, nullptr, nullptr, Zgl);
  invz_kernel<<<64, 256, 0, stream>>>(Zgl, invZgl);
  cc_kernel<<<dim3(NI, BATCH), 256, 0, stream>>>(bigW, invZgl, cs2v, ccv);

  // Abig = [[L1u/Z | L1L1u],[L2u/Z | L2L2u]] bf16
  mgemm<64, 64, 4><<<dim3(16, 4, BATCH), 256, 0, stream>>>(
      stack4, xuaiTb, nullptr, CE, CE, CE, CE, 0, S1,
      nullptr, Abig, 0, (long long)128 * 2048, invZgl, nullptr, nullptr, nullptr, nullptr);

  // fused: Tacc = Abig @ [W ; G12t] + b2 (x) cc + (L2 b2) (x) v2
  mgemm<64, 128, 5><<<dim3(8, 2, BATCH), 256, 0, stream>>>(
      Abig, bigW, G12b, NI, 2 * NI, 2048, NI, (long long)128 * 2048, NN2,
      Tacc, nullptr, NI, S2, ccv, v2v, rb2ext, rl2ext, nullptr);

  // layernorm: parallel two-phase, apply fused with final gating
  ln_reduce<<<dim3(BATCH, 2, 16), 256, 0, stream>>>(Tacc, stats);
  ln_final<<<(int)(BCN / 256), 256, 0, stream>>>(Tacc, stats, ln_w, ln_b, ct, xuaiTf, outp);
}